// Round 13
// baseline (72.112 us; speedup 1.0000x reference)
//
#include <hip/hip_runtime.h>
#include <hip/hip_bf16.h>
#include <math.h>

// out[b,f,t] = sum_l sig[b,l] * win[t,l] * cos(2*pi*fv[f]*l/8192)
// R13 = R12 (single dispatch, zero ws, register-direct fragments) with 2x
// waves/SIMD: 512-thread blocks (8 waves, each K/8=1024 -> 32 steps), LDS
// Sg unioned with the post-loop Acc buffer (32 KB -> still 2 blocks/CU),
// __launch_bounds__(512,4) (128 VGPR cap, ~115 est live).
// Gaussian: multiplicative recurrence; cos: stride-32 Chebyshev ping-pong
// seeded from exact integer phase mod 8192 (R0-verified fv/tc).

#define L_ 8192
#define B_ 32

typedef _Float16 half8 __attribute__((ext_vector_type(8)));
typedef __fp16 fp16x2 __attribute__((ext_vector_type(2)));
typedef float float2v __attribute__((ext_vector_type(2)));
typedef float float4v __attribute__((ext_vector_type(4)));

#define H_ 0.001220703125f                 // 1/819.2 = 5/4096 (exact)
#define CSTEP_ 7.66990393942594528198e-4f  // 2*pi/8192

__global__ __launch_bounds__(512, 4) void gabor_kernel(
    const float* __restrict__ signal, float* __restrict__ out) {
  const int bx = blockIdx.x;  // 512 = b32 * th4 * fh4
  const int b = bx & 31;
  const int th = (bx >> 5) & 3;
  const int fh = (bx >> 7) & 3;
  const int tid = threadIdx.x;  // 512
  const int lane = tid & 63;
  const int wv = tid >> 6;      // 0..7
  const int frow = lane & 15;
  const int quad = lane >> 4;

  // LDS union: Sg lives during the K-loop, Acc only after it.
  __shared__ __align__(16) char smraw[32768];
  _Float16* Sg = (_Float16*)smraw;                   // [8192] f16, 16 KB
  float4v (*Acc)[64][4] = (float4v(*)[64][4])smraw;  // [8][64][4], 32 KB

  // ---- stage sig row b (once) ----
  {
    const float* srow = signal + (size_t)b * L_;
#pragma unroll
    for (int i = 0; i < 2; ++i) {
      const int off = i * 4096 + tid * 8;
      float4v s0 = *(const float4v*)(srow + off);
      float4v s1 = *(const float4v*)(srow + off + 4);
      union { fp16x2 h2[4]; half8 h8; } sh;
      sh.h2[0] = __builtin_amdgcn_cvt_pkrtz(s0[0], s0[1]);
      sh.h2[1] = __builtin_amdgcn_cvt_pkrtz(s0[2], s0[3]);
      sh.h2[2] = __builtin_amdgcn_cvt_pkrtz(s1[0], s1[1]);
      sh.h2[3] = __builtin_amdgcn_cvt_pkrtz(s1[2], s1[3]);
      *(half8*)&Sg[off] = sh.h8;
    }
  }
  __syncthreads();

  const int t0 = th * 32;
  const int f0 = fh * 32;
  const int k0 = wv * 1024 + quad * 8;  // this wave's first element (j=0)

  // ---- per-lane fragment state (packed f32 pairs) ----
  float2v w2[2][4], Rw2[2][4];   // Gaussian value + step-ratio
  float2v cE2[2][4], cO2[2][4];  // Chebyshev ping-pong (even/odd step)
  float2v K32v[2];
  const float2v Q32v = {0.99847528338432312012f,
                        0.99847528338432312012f};  // exp(-1024*H^2)
#pragma unroll
  for (int fr = 0; fr < 2; ++fr) {
    const float tc = truncf((float)(t0 + fr * 16 + frow) * (8191.0f / 127.0f));
    const int fv = (int)((float)(f0 + fr * 16 + frow) * (4096.0f / 127.0f));
    const float K32 = 2.0f * __cosf((float)((fv * 32) & (L_ - 1)) * CSTEP_);
    K32v[fr] = (float2v){K32, K32};
#pragma unroll
    for (int q = 0; q < 4; ++q) {
#pragma unroll
      for (int h = 0; h < 2; ++h) {
        const int j = 2 * q + h;
        const float x = ((float)(k0 + j) - tc) * H_;
        w2[fr][q][h] = __expf(-0.5f * x * x);
        // ratio for k += 32: exp(-32*H*x - 512*H^2)
        Rw2[fr][q][h] =
            __expf(__builtin_fmaf(-0.0390625f, x, -7.62939453125e-4f));
        cE2[fr][q][h] = __cosf((float)((fv * (k0 + j)) & (L_ - 1)) * CSTEP_);
        // value at k-32 (k0+j+8160 == k0+j-32 mod 8192)
        cO2[fr][q][h] =
            __cosf((float)((fv * (k0 + j + 8160)) & (L_ - 1)) * CSTEP_);
      }
    }
  }

  float4v acc[2][2];  // [fr1 t][fr2 f]
#pragma unroll
  for (int i = 0; i < 2; ++i)
#pragma unroll
    for (int j = 0; j < 2; ++j) acc[i][j] = (float4v)(0.0f);

  union H8 { fp16x2 h2[4]; half8 h8; };

  // ---- 32 K-steps: 16 rolled iterations x 2 ping-pong sub-steps ----
#pragma unroll 1
  for (int p = 0; p < 16; ++p) {
    // even sub-step (k = k0 + (2p)*32)
    {
      H8 ha[2], hc[2];
#pragma unroll
      for (int fr = 0; fr < 2; ++fr)
#pragma unroll
        for (int q = 0; q < 4; ++q) {
          ha[fr].h2[q] = __builtin_amdgcn_cvt_pkrtz(w2[fr][q][0], w2[fr][q][1]);
          hc[fr].h2[q] = __builtin_amdgcn_cvt_pkrtz(cE2[fr][q][0], cE2[fr][q][1]);
        }
      const half8 sgv = *(const half8*)&Sg[k0 + (2 * p) * 32];
#pragma unroll
      for (int fr2 = 0; fr2 < 2; ++fr2) {
        const half8 hbf = hc[fr2].h8 * sgv;
        acc[0][fr2] = __builtin_amdgcn_mfma_f32_16x16x32_f16(ha[0].h8, hbf,
                                                             acc[0][fr2], 0, 0, 0);
        acc[1][fr2] = __builtin_amdgcn_mfma_f32_16x16x32_f16(ha[1].h8, hbf,
                                                             acc[1][fr2], 0, 0, 0);
      }
#pragma unroll
      for (int fr = 0; fr < 2; ++fr)
#pragma unroll
        for (int q = 0; q < 4; ++q) {
          w2[fr][q] *= Rw2[fr][q];
          Rw2[fr][q] *= Q32v;
          cO2[fr][q] = __builtin_elementwise_fma(K32v[fr], cE2[fr][q], -cO2[fr][q]);
        }
    }
    // odd sub-step (k = k0 + (2p+1)*32)
    {
      H8 ha[2], hc[2];
#pragma unroll
      for (int fr = 0; fr < 2; ++fr)
#pragma unroll
        for (int q = 0; q < 4; ++q) {
          ha[fr].h2[q] = __builtin_amdgcn_cvt_pkrtz(w2[fr][q][0], w2[fr][q][1]);
          hc[fr].h2[q] = __builtin_amdgcn_cvt_pkrtz(cO2[fr][q][0], cO2[fr][q][1]);
        }
      const half8 sgv = *(const half8*)&Sg[k0 + (2 * p + 1) * 32];
#pragma unroll
      for (int fr2 = 0; fr2 < 2; ++fr2) {
        const half8 hbf = hc[fr2].h8 * sgv;
        acc[0][fr2] = __builtin_amdgcn_mfma_f32_16x16x32_f16(ha[0].h8, hbf,
                                                             acc[0][fr2], 0, 0, 0);
        acc[1][fr2] = __builtin_amdgcn_mfma_f32_16x16x32_f16(ha[1].h8, hbf,
                                                             acc[1][fr2], 0, 0, 0);
      }
#pragma unroll
      for (int fr = 0; fr < 2; ++fr)
#pragma unroll
        for (int q = 0; q < 4; ++q) {
          w2[fr][q] *= Rw2[fr][q];
          Rw2[fr][q] *= Q32v;
          cE2[fr][q] = __builtin_elementwise_fma(K32v[fr], cO2[fr][q], -cE2[fr][q]);
        }
    }
  }

  // ---- combine 8 waves' K-partials through LDS (reusing Sg space) ----
  __syncthreads();  // all Sg reads complete before overwrite
#pragma unroll
  for (int i4 = 0; i4 < 4; ++i4)
    Acc[wv][lane][i4] = acc[i4 >> 1][i4 & 1];  // i4 = fr1*2 + fr2
  __syncthreads();
  if (wv < 4) {
    float4v sum = Acc[0][lane][wv];
#pragma unroll
    for (int w = 1; w < 8; ++w) sum += Acc[w][lane][wv];
    const int fr1 = wv >> 1, fr2 = wv & 1;
    const int f = f0 + fr2 * 16 + frow;
    const int t = t0 + fr1 * 16 + quad * 4;
    // D frag: col(f)=lane&15, row(t)=quad*4+reg (reg contiguous in t)
    *(float4v*)(out + ((size_t)(b * 128 + f)) * 128 + t) = sum;
  }
}

extern "C" void kernel_launch(void* const* d_in, const int* in_sizes, int n_in,
                              void* d_out, int out_size, void* d_ws, size_t ws_size,
                              hipStream_t stream) {
  const float* signal = (const float*)d_in[0];
  float* out = (float*)d_out;
  gabor_kernel<<<dim3(512), dim3(512), 0, stream>>>(signal, out);
}

// Round 14
// 68.035 us; speedup vs baseline: 1.0599x; 1.0599x over previous
//
#include <hip/hip_runtime.h>
#include <hip/hip_bf16.h>
#include <math.h>

// out[b,f,t] = sum_l sig[b,l] * win[t,l] * cos(2*pi*fv[f]*l/8192)
// R14 = R13 (single dispatch, zero ws, register-direct fragments) + 2-b
// amortization: each block computes a 32t x 32f tile for TWO b's, reusing
// the win/cos fragments (b-independent) for both -> fragment-gen VALU per
// MFMA drops 12 -> 7 instr. 256 blocks x 512 threads (8 waves, K/8 each),
// Sg[2][8192] (32 KB) unioned with the post-loop reduction buffer,
// two-phase LDS reduce. __launch_bounds__(512,2), ~135 VGPR est.
// Gaussian: multiplicative recurrence; cos: stride-32 Chebyshev ping-pong
// seeded from exact integer phase mod 8192 (R0-verified fv/tc).

#define L_ 8192
#define B_ 32

typedef _Float16 half8 __attribute__((ext_vector_type(8)));
typedef __fp16 fp16x2 __attribute__((ext_vector_type(2)));
typedef float float2v __attribute__((ext_vector_type(2)));
typedef float float4v __attribute__((ext_vector_type(4)));

#define H_ 0.001220703125f                 // 1/819.2 = 5/4096 (exact)
#define CSTEP_ 7.66990393942594528198e-4f  // 2*pi/8192

__global__ __launch_bounds__(512, 2) void gabor_kernel(
    const float* __restrict__ signal, float* __restrict__ out) {
  const int bx = blockIdx.x;  // 256 = bpair16 * th4 * fh4
  const int bp = bx & 15;     // b-pair: b = 2*bp, 2*bp+1
  const int th = (bx >> 4) & 3;
  const int fh = (bx >> 6) & 3;
  const int tid = threadIdx.x;  // 512
  const int lane = tid & 63;
  const int wv = tid >> 6;      // 0..7
  const int frow = lane & 15;
  const int quad = lane >> 4;

  // LDS union: Sg lives during the K-loop, Acc (reduction) after it.
  __shared__ __align__(16) char smraw[32768];
  _Float16(*Sg)[L_] = (_Float16(*)[L_])smraw;        // [2][8192] f16, 32 KB
  float4v(*Acc)[64][4] = (float4v(*)[64][4])smraw;   // [8][64][4], 32 KB

  // ---- stage sig rows 2bp, 2bp+1 (once) ----
  {
#pragma unroll
    for (int bi = 0; bi < 2; ++bi) {
      const float* srow = signal + (size_t)(2 * bp + bi) * L_;
#pragma unroll
      for (int i = 0; i < 2; ++i) {
        const int off = i * 4096 + tid * 8;
        float4v s0 = *(const float4v*)(srow + off);
        float4v s1 = *(const float4v*)(srow + off + 4);
        union { fp16x2 h2[4]; half8 h8; } sh;
        sh.h2[0] = __builtin_amdgcn_cvt_pkrtz(s0[0], s0[1]);
        sh.h2[1] = __builtin_amdgcn_cvt_pkrtz(s0[2], s0[3]);
        sh.h2[2] = __builtin_amdgcn_cvt_pkrtz(s1[0], s1[1]);
        sh.h2[3] = __builtin_amdgcn_cvt_pkrtz(s1[2], s1[3]);
        *(half8*)&Sg[bi][off] = sh.h8;
      }
    }
  }
  __syncthreads();

  const int t0 = th * 32;
  const int f0 = fh * 32;
  const int k0 = wv * 1024 + quad * 8;  // this wave's first element (j=0)

  // ---- per-lane fragment state (packed f32 pairs) ----
  float2v w2[2][4], Rw2[2][4];   // Gaussian value + step-ratio
  float2v cE2[2][4], cO2[2][4];  // Chebyshev ping-pong (even/odd step)
  float2v K32v[2];
  const float2v Q32v = {0.99847528338432312012f,
                        0.99847528338432312012f};  // exp(-1024*H^2)
#pragma unroll
  for (int fr = 0; fr < 2; ++fr) {
    const float tc = truncf((float)(t0 + fr * 16 + frow) * (8191.0f / 127.0f));
    const int fv = (int)((float)(f0 + fr * 16 + frow) * (4096.0f / 127.0f));
    const float K32 = 2.0f * __cosf((float)((fv * 32) & (L_ - 1)) * CSTEP_);
    K32v[fr] = (float2v){K32, K32};
#pragma unroll
    for (int q = 0; q < 4; ++q) {
#pragma unroll
      for (int h = 0; h < 2; ++h) {
        const int j = 2 * q + h;
        const float x = ((float)(k0 + j) - tc) * H_;
        w2[fr][q][h] = __expf(-0.5f * x * x);
        // ratio for k += 32: exp(-32*H*x - 512*H^2)
        Rw2[fr][q][h] =
            __expf(__builtin_fmaf(-0.0390625f, x, -7.62939453125e-4f));
        cE2[fr][q][h] = __cosf((float)((fv * (k0 + j)) & (L_ - 1)) * CSTEP_);
        // value at k-32 (k0+j+8160 == k0+j-32 mod 8192)
        cO2[fr][q][h] =
            __cosf((float)((fv * (k0 + j + 8160)) & (L_ - 1)) * CSTEP_);
      }
    }
  }

  float4v acc[2][2][2];  // [fr1 t][fr2 f][bi]
#pragma unroll
  for (int i = 0; i < 2; ++i)
#pragma unroll
    for (int j = 0; j < 2; ++j)
#pragma unroll
      for (int bi = 0; bi < 2; ++bi) acc[i][j][bi] = (float4v)(0.0f);

  union H8 { fp16x2 h2[4]; half8 h8; };

  // ---- 32 K-steps: 16 rolled iterations x 2 ping-pong sub-steps ----
#pragma unroll 1
  for (int p = 0; p < 16; ++p) {
    // even sub-step (k = k0 + (2p)*32)
    {
      H8 ha[2], hc[2];
#pragma unroll
      for (int fr = 0; fr < 2; ++fr)
#pragma unroll
        for (int q = 0; q < 4; ++q) {
          ha[fr].h2[q] = __builtin_amdgcn_cvt_pkrtz(w2[fr][q][0], w2[fr][q][1]);
          hc[fr].h2[q] = __builtin_amdgcn_cvt_pkrtz(cE2[fr][q][0], cE2[fr][q][1]);
        }
      const int kk = k0 + (2 * p) * 32;
      const half8 sg0 = *(const half8*)&Sg[0][kk];
      const half8 sg1 = *(const half8*)&Sg[1][kk];
#pragma unroll
      for (int fr2 = 0; fr2 < 2; ++fr2) {
        const half8 hb0 = hc[fr2].h8 * sg0;
        const half8 hb1 = hc[fr2].h8 * sg1;
        acc[0][fr2][0] = __builtin_amdgcn_mfma_f32_16x16x32_f16(
            ha[0].h8, hb0, acc[0][fr2][0], 0, 0, 0);
        acc[1][fr2][0] = __builtin_amdgcn_mfma_f32_16x16x32_f16(
            ha[1].h8, hb0, acc[1][fr2][0], 0, 0, 0);
        acc[0][fr2][1] = __builtin_amdgcn_mfma_f32_16x16x32_f16(
            ha[0].h8, hb1, acc[0][fr2][1], 0, 0, 0);
        acc[1][fr2][1] = __builtin_amdgcn_mfma_f32_16x16x32_f16(
            ha[1].h8, hb1, acc[1][fr2][1], 0, 0, 0);
      }
#pragma unroll
      for (int fr = 0; fr < 2; ++fr)
#pragma unroll
        for (int q = 0; q < 4; ++q) {
          w2[fr][q] *= Rw2[fr][q];
          Rw2[fr][q] *= Q32v;
          cO2[fr][q] = __builtin_elementwise_fma(K32v[fr], cE2[fr][q], -cO2[fr][q]);
        }
    }
    // odd sub-step (k = k0 + (2p+1)*32)
    {
      H8 ha[2], hc[2];
#pragma unroll
      for (int fr = 0; fr < 2; ++fr)
#pragma unroll
        for (int q = 0; q < 4; ++q) {
          ha[fr].h2[q] = __builtin_amdgcn_cvt_pkrtz(w2[fr][q][0], w2[fr][q][1]);
          hc[fr].h2[q] = __builtin_amdgcn_cvt_pkrtz(cO2[fr][q][0], cO2[fr][q][1]);
        }
      const int kk = k0 + (2 * p + 1) * 32;
      const half8 sg0 = *(const half8*)&Sg[0][kk];
      const half8 sg1 = *(const half8*)&Sg[1][kk];
#pragma unroll
      for (int fr2 = 0; fr2 < 2; ++fr2) {
        const half8 hb0 = hc[fr2].h8 * sg0;
        const half8 hb1 = hc[fr2].h8 * sg1;
        acc[0][fr2][0] = __builtin_amdgcn_mfma_f32_16x16x32_f16(
            ha[0].h8, hb0, acc[0][fr2][0], 0, 0, 0);
        acc[1][fr2][0] = __builtin_amdgcn_mfma_f32_16x16x32_f16(
            ha[1].h8, hb0, acc[1][fr2][0], 0, 0, 0);
        acc[0][fr2][1] = __builtin_amdgcn_mfma_f32_16x16x32_f16(
            ha[0].h8, hb1, acc[0][fr2][1], 0, 0, 0);
        acc[1][fr2][1] = __builtin_amdgcn_mfma_f32_16x16x32_f16(
            ha[1].h8, hb1, acc[1][fr2][1], 0, 0, 0);
      }
#pragma unroll
      for (int fr = 0; fr < 2; ++fr)
#pragma unroll
        for (int q = 0; q < 4; ++q) {
          w2[fr][q] *= Rw2[fr][q];
          Rw2[fr][q] *= Q32v;
          cE2[fr][q] = __builtin_elementwise_fma(K32v[fr], cO2[fr][q], -cE2[fr][q]);
        }
    }
  }

  // ---- two-phase reduction through LDS (reusing Sg space) ----
  // D frag: col(f)=lane&15, row(t)=quad*4+reg (reg contiguous in t)
#pragma unroll
  for (int bi = 0; bi < 2; ++bi) {
    __syncthreads();  // phase bi: previous LDS use complete
#pragma unroll
    for (int i4 = 0; i4 < 4; ++i4)
      Acc[wv][lane][i4] = acc[i4 >> 1][i4 & 1][bi];  // i4 = fr1*2 + fr2
    __syncthreads();
    if (wv < 4) {
      float4v sum = Acc[0][lane][wv];
#pragma unroll
      for (int w = 1; w < 8; ++w) sum += Acc[w][lane][wv];
      const int fr1 = wv >> 1, fr2 = wv & 1;
      const int f = f0 + fr2 * 16 + frow;
      const int t = t0 + fr1 * 16 + quad * 4;
      *(float4v*)(out + ((size_t)((2 * bp + bi) * 128 + f)) * 128 + t) = sum;
    }
  }
}

extern "C" void kernel_launch(void* const* d_in, const int* in_sizes, int n_in,
                              void* d_out, int out_size, void* d_ws, size_t ws_size,
                              hipStream_t stream) {
  const float* signal = (const float*)d_in[0];
  float* out = (float*)d_out;
  gabor_kernel<<<dim3(256), dim3(512), 0, stream>>>(signal, out);
}